// Round 24
// baseline (1136.416 us; speedup 1.0000x reference)
//
#include <hip/hip_runtime.h>
#include <math.h>

#define HD 56
#define WD 56
#define NPIX 3136   // 56*56
#define NBATCH 8

// ---------------- generic conv (3x3 or 1x1), 64px x 64co tile ----------------
// NCHW=true : in is (B, Cin, 3136) NCHW flat (used for the raw input x, Cin=128)
// NCHW=false: in is (25088, Cin) NHWC flat
// wgt: (TAPS, Cin, Cout) HWIO-flat   out: (25088, Cout) NHWC flat
template <bool RELU, int TAPS, bool NCHW>
__global__ __launch_bounds__(256) void conv_co64(const float* __restrict__ in,
                                                 const float* __restrict__ wgt,
                                                 const float* __restrict__ bias,
                                                 float* __restrict__ out,
                                                 const int Cin, const int Cout,
                                                 const float scale) {
  __shared__ float As[32][64];   // [k][pixel]
  __shared__ float Bs[32][64];   // [k][cout]
  const int t  = threadIdx.x;
  const int p0 = blockIdx.x * 64;          // pixel tile; 3136%64==0 so never crosses batch
  int co0 = blockIdx.y * 64;
  if (co0 + 64 > Cout) co0 = Cout - 64;    // overlap tiles write identical values (benign)

  // A-staging geometry
  const int pa = NCHW ? (t & 63) : (t >> 2);      // pixel within tile
  const int ka = NCHW ? 0 : (t & 3) * 8;          // NHWC: 8 consecutive k per lane
  const int kr = NCHW ? (t >> 6) * 8 : 0;         // NCHW: 8 k-rows per lane group
  const int gp = p0 + pa;
  const int bb = gp / NPIX;
  const int p2 = gp - bb * NPIX;
  const int ph = p2 / WD, pw = p2 - ph * WD;
  const float* const srcb = NCHW ? (in + (size_t)bb * Cin * NPIX)
                                 : (in + (size_t)gp * Cin);
  // B-staging geometry
  const int kb = t >> 4;                   // 0..15 (+16)
  const int cb = (t & 15) * 4;
  // compute mapping: 4px x 4co per thread
  const int ci = t >> 4;
  const int cj = t & 15;
  float acc[4][4] = {};

  for (int tap = 0; tap < TAPS; ++tap) {
    const int dy = (TAPS == 1) ? 0 : (tap / 3 - 1);
    const int dx = (TAPS == 1) ? 0 : (tap % 3 - 1);
    const bool valid = ((unsigned)(ph + dy) < (unsigned)HD) &&
                       ((unsigned)(pw + dx) < (unsigned)WD);
    const int spix = p2 + dy * WD + dx;               // shifted pixel (NCHW path)
    const float* const wt = wgt + (size_t)tap * Cin * Cout + co0;
    for (int cc = 0; cc < Cin; cc += 32) {
      __syncthreads();
      if constexpr (NCHW) {
#pragma unroll
        for (int i = 0; i < 8; ++i)
          As[kr + i][pa] = valid ? srcb[(size_t)(cc + kr + i) * NPIX + spix] : 0.f;
      } else {
        float4 a0 = {0.f, 0.f, 0.f, 0.f}, a1 = {0.f, 0.f, 0.f, 0.f};
        const float* s = srcb + (ptrdiff_t)(dy * WD + dx) * Cin + cc + ka;
        if (valid) { a0 = *(const float4*)s; a1 = *(const float4*)(s + 4); }
        As[ka + 0][pa] = a0.x; As[ka + 1][pa] = a0.y;
        As[ka + 2][pa] = a0.z; As[ka + 3][pa] = a0.w;
        As[ka + 4][pa] = a1.x; As[ka + 5][pa] = a1.y;
        As[ka + 6][pa] = a1.z; As[ka + 7][pa] = a1.w;
      }
      const float4 b0 = *(const float4*)(wt + (size_t)(cc + kb) * Cout + cb);
      const float4 b1 = *(const float4*)(wt + (size_t)(cc + kb + 16) * Cout + cb);
      *(float4*)&Bs[kb][cb]      = b0;
      *(float4*)&Bs[kb + 16][cb] = b1;
      __syncthreads();
#pragma unroll
      for (int k = 0; k < 32; ++k) {
        float av[4], bv[4];
        *(float4*)av = *(const float4*)&As[k][ci * 4];
        *(float4*)bv = *(const float4*)&Bs[k][cj * 4];
#pragma unroll
        for (int q = 0; q < 4; ++q)
#pragma unroll
          for (int r = 0; r < 4; ++r)
            acc[q][r] = fmaf(av[q], bv[r], acc[q][r]);
      }
    }
  }
#pragma unroll
  for (int q = 0; q < 4; ++q) {
    const int gpo = p0 + ci * 4 + q;
    float vv[4];
#pragma unroll
    for (int r = 0; r < 4; ++r) {
      float xv = (acc[q][r] + bias[co0 + cj * 4 + r]) * scale;
      if (RELU) xv = fmaxf(xv, 0.f);
      vv[r] = xv;
    }
    *(float4*)(out + (size_t)gpo * Cout + co0 + cj * 4) = *(const float4*)vv;
  }
}

// ---------------- conv3: 3x3, 256 -> 16, 256px x 16co tile ----------------
__global__ __launch_bounds__(256) void conv3_k(const float* __restrict__ in,   // (25088,256)
                                               const float* __restrict__ wgt,  // (9,256,16)
                                               const float* __restrict__ bias, // 16
                                               float* __restrict__ out) {      // (25088,16)
  __shared__ float As[32][256];
  __shared__ float Bs[32][16];
  const int t  = threadIdx.x;
  const int p0 = blockIdx.x * 256;   // may cross batch; handled per-pixel
  const int spx = t >> 2;            // 0..63
  const int ka  = (t & 3) * 8;
  int hh[4], wwv[4];
  const float* sb[4];
#pragma unroll
  for (int ps = 0; ps < 4; ++ps) {
    const int gp = p0 + ps * 64 + spx;
    const int p2 = gp % NPIX;
    hh[ps]  = p2 / WD;
    wwv[ps] = p2 % WD;
    sb[ps]  = in + (size_t)gp * 256;
  }
  const int kb  = t >> 3;            // 0..31
  const int cbb = (t & 7) * 2;
  const int ci  = t >> 2;            // pixel group 0..63
  const int cj  = t & 3;             // co group 0..3
  float acc[4][4] = {};

  for (int tap = 0; tap < 9; ++tap) {
    const int dy  = tap / 3 - 1, dx = tap % 3 - 1;
    const ptrdiff_t del = (ptrdiff_t)(dy * WD + dx) * 256;
    for (int cc = 0; cc < 256; cc += 32) {
      __syncthreads();
#pragma unroll
      for (int ps = 0; ps < 4; ++ps) {
        const int y = hh[ps] + dy, xw = wwv[ps] + dx;
        float4 a0 = {0.f, 0.f, 0.f, 0.f}, a1 = {0.f, 0.f, 0.f, 0.f};
        if ((unsigned)y < (unsigned)HD && (unsigned)xw < (unsigned)WD) {
          const float* s = sb[ps] + del + cc + ka;
          a0 = *(const float4*)s;
          a1 = *(const float4*)(s + 4);
        }
        const int pxl = ps * 64 + spx;
        As[ka + 0][pxl] = a0.x; As[ka + 1][pxl] = a0.y;
        As[ka + 2][pxl] = a0.z; As[ka + 3][pxl] = a0.w;
        As[ka + 4][pxl] = a1.x; As[ka + 5][pxl] = a1.y;
        As[ka + 6][pxl] = a1.z; As[ka + 7][pxl] = a1.w;
      }
      *(float2*)&Bs[kb][cbb] =
          *(const float2*)(wgt + (size_t)(tap * 256 + cc + kb) * 16 + cbb);
      __syncthreads();
#pragma unroll
      for (int k = 0; k < 32; ++k) {
        float av[4], bv[4];
        *(float4*)av = *(const float4*)&As[k][ci * 4];
        *(float4*)bv = *(const float4*)&Bs[k][cj * 4];
#pragma unroll
        for (int q = 0; q < 4; ++q)
#pragma unroll
          for (int r = 0; r < 4; ++r)
            acc[q][r] = fmaf(av[q], bv[r], acc[q][r]);
      }
    }
  }
#pragma unroll
  for (int q = 0; q < 4; ++q) {
    const int gpo = p0 + ci * 4 + q;
    float vv[4];
#pragma unroll
    for (int r = 0; r < 4; ++r) vv[r] = acc[q][r] + bias[cj * 4 + r];
    *(float4*)(out + (size_t)gpo * 16 + cj * 4) = *(const float4*)vv;
  }
}

// ---------------- final: softmax over 9 taps + scrambled-patch combine ----------------
// c3: (25088,16).  m2: per-batch NHWC flat (451584), read raw as (144,3136).
// out: (8,16,224,224)
__global__ __launch_bounds__(256) void final_kernel(const float* __restrict__ c3,
                                                    const float* __restrict__ m2,
                                                    float* __restrict__ out) {
  __shared__ float P[16][145];
  const int t   = threadIdx.x;
  const int gp0 = blockIdx.x * 16;
  {  // stage scrambled patches: 16 px x 144 j
    const int px = t >> 4;
    const int jg = t & 15;
    const int gp = gp0 + px;
    const int b  = gp / NPIX;
    const int p2 = gp % NPIX;
    const int h2 = p2 / WD, w2 = p2 % WD;
    const float* c3b = c3 + ((size_t)b * NPIX + (size_t)h2 * WD) * 16;
#pragma unroll
    for (int i = 0; i < 9; ++i) {
      const int j  = jg * 9 + i;            // j = o*9 + t2
      const int f  = w2 * 144 + j;
      const int t9 = f / 896;               // tap in scrambled (w,channel) space
      const int rr = f - t9 * 896;
      const int w  = rr >> 4;
      const int c  = rr & 15;
      const int wy = w + t9 / 3 - 1;        // shift w by ky
      const int cx = c + t9 % 3 - 1;        // shift CHANNEL by kx (reference quirk)
      float v = 0.f;
      if ((unsigned)wy < (unsigned)WD && (unsigned)cx < 16u) v = c3b[wy * 16 + cx];
      P[px][j] = v;
    }
  }
  __syncthreads();
  const int px = t >> 4;
  const int uv = t & 15;
  const int gp = gp0 + px;
  const int b  = gp / NPIX;
  const int p2 = gp % NPIX;
  const int h2 = p2 / WD, w2 = p2 % WD;
  const float* mb = m2 + (size_t)b * 451584 + p2;
  float e[9];
  float mx = -1e30f;
#pragma unroll
  for (int t2 = 0; t2 < 9; ++t2) {
    e[t2] = mb[(size_t)(t2 * 16 + uv) * NPIX];
    mx = fmaxf(mx, e[t2]);
  }
  float s = 0.f;
#pragma unroll
  for (int t2 = 0; t2 < 9; ++t2) { e[t2] = expf(e[t2] - mx); s += e[t2]; }
  const float inv = 1.f / s;
#pragma unroll
  for (int t2 = 0; t2 < 9; ++t2) e[t2] *= inv;
  const int u = uv >> 2, v = uv & 3;
  float* ob = out + (size_t)b * 16 * 224 * 224 + (size_t)(h2 * 4 + u) * 224 + (w2 * 4 + v);
#pragma unroll
  for (int o = 0; o < 16; ++o) {
    float acc = 0.f;
#pragma unroll
    for (int t2 = 0; t2 < 9; ++t2) acc = fmaf(P[px][o * 9 + t2], e[t2], acc);
    ob[(size_t)o * 224 * 224] = acc;
  }
}

extern "C" void kernel_launch(void* const* d_in, const int* in_sizes, int n_in,
                              void* d_out, int out_size, void* d_ws, size_t ws_size,
                              hipStream_t stream) {
  (void)in_sizes; (void)n_in; (void)out_size; (void)ws_size;
  const float* x   = (const float*)d_in[0];
  const float* w1  = (const float*)d_in[1];
  const float* b1  = (const float*)d_in[2];
  const float* w2  = (const float*)d_in[3];
  const float* b2  = (const float*)d_in[4];
  const float* w3  = (const float*)d_in[5];
  const float* b3  = (const float*)d_in[6];
  const float* mw1 = (const float*)d_in[7];
  const float* mb1 = (const float*)d_in[8];
  const float* mw2 = (const float*)d_in[9];
  const float* mb2 = (const float*)d_in[10];
  float* out = (float*)d_out;
  float* ws  = (float*)d_ws;

  // Buffer plan (d_out doubles as scratch; peak d_ws use = 27,295,744 bytes):
  //   c1 -> d_out (6,422,528 f)        [dead after conv2]
  //   c2 -> ws[0 : 6,422,528]          [dead after conv3]
  //   m1 -> d_out (overwrites dead c1) [dead after conv_m2]
  //   c3 -> ws[6,422,528 : 6,823,936]
  //   m2 -> ws[0 : 3,612,672]          (overwrites dead c2)
  //   final -> d_out (overwrites dead m1)
  float* c1 = out;
  float* c2 = ws;
  float* m1 = out;
  float* c3 = ws + 6422528;
  float* m2 = ws;

  conv_co64<true, 9, true><<<dim3(392, 4), dim3(256), 0, stream>>>(x, w1, b1, c1, 128, 256, 1.0f);
  conv_co64<true, 9, false><<<dim3(392, 4), dim3(256), 0, stream>>>(c1, w2, b2, c2, 256, 256, 1.0f);
  conv_co64<true, 9, true><<<dim3(392, 4), dim3(256), 0, stream>>>(x, mw1, mb1, m1, 128, 256, 1.0f);
  conv3_k<<<dim3(98), dim3(256), 0, stream>>>(c2, w3, b3, c3);
  conv_co64<false, 1, false><<<dim3(392, 3), dim3(256), 0, stream>>>(m1, mw2, mb2, m2, 256, 144, 0.1f);
  final_kernel<<<dim3(1568), dim3(256), 0, stream>>>(c3, m2, out);
}